// Round 6
// baseline (138.400 us; speedup 1.0000x reference)
//
#include <hip/hip_runtime.h>
#include <hip/hip_bf16.h>

#define C_   512
#define HS   128
#define NN   10368   // 18*24*24 ; 648 n-tiles of 16

typedef __bf16 bf16x8 __attribute__((ext_vector_type(8)));
typedef __bf16 bf16x4 __attribute__((ext_vector_type(4)));
typedef __bf16 bf16x2 __attribute__((ext_vector_type(2)));
typedef float  f32x4  __attribute__((ext_vector_type(4)));

__device__ __forceinline__ bf16x8 load_f32x8_as_bf16(const float* __restrict__ p) {
    float4 v0 = *(const float4*)p;
    float4 v1 = *(const float4*)(p + 4);
    bf16x8 o;
    o[0] = (__bf16)v0.x; o[1] = (__bf16)v0.y; o[2] = (__bf16)v0.z; o[3] = (__bf16)v0.w;
    o[4] = (__bf16)v1.x; o[5] = (__bf16)v1.y; o[6] = (__bf16)v1.z; o[7] = (__bf16)v1.w;
    return o;
}

// ---------------------------------------------------------------------------
// K0 (prep): 20 blocks x 256.  (r5 verbatim)
//   b<4 : convert Wj,Wi fp32->bf16.   b>=4: zero Mtf fp32 [C][HS].
// ---------------------------------------------------------------------------
__global__ __launch_bounds__(256, 2)
void k_prep(const float* __restrict__ Wi, const float* __restrict__ Wj,
            __bf16* __restrict__ Wib, __bf16* __restrict__ Wjb,
            float* __restrict__ Mtf) {
    const int b = blockIdx.x;
    const int t = threadIdx.x;
    if (b < 4) {   // b=0,1 -> Wjb ; b=2,3 -> Wib
        const float* src = (b < 2) ? Wj : Wi;
        __bf16* dst = (b < 2) ? Wjb : Wib;
        const int off = (b & 1) * 32768;
        #pragma unroll 4
        for (int u = 0; u < 32; u++) {
            const int idx = off + u * 1024 + t * 4;
            float4 v = *(const float4*)(src + idx);
            bf16x4 o;
            o[0] = (__bf16)v.x; o[1] = (__bf16)v.y;
            o[2] = (__bf16)v.z; o[3] = (__bf16)v.w;
            *(bf16x4*)(dst + idx) = o;
        }
    } else {       // zero Mtf: 16 blocks x 256 thr x 16 floats
        const int z = b - 4;
        f32x4 zv = {0.f, 0.f, 0.f, 0.f};
        float* p = Mtf + z * 4096 + t * 16;
        *(f32x4*)(p) = zv; *(f32x4*)(p + 4) = zv;
        *(f32x4*)(p + 8) = zv; *(f32x4*)(p + 12) = zv;
    }
}

// ---------------------------------------------------------------------------
// K1 (fused transpose + G1 + G2), 648 blocks x 256 thr — n-tile 16:
//   stage (float4): thread = (n-quad t&3, c-lane t>>2); 8 float4 feat loads,
//     bf16x4 xb stores, scalar LDS scatter into xt[16][520] (verified layout,
//     rows halved from r5's [32][520]).
//   compute (4 waves, wave w: h0 = 32w) — r5 verified mappings, n-16-tile
//     index pinned to 0:
//       fj[h][n]   = sum_c Wj[h][c]*x[c][n] + bj[h]   (A=Wjb bf16x8, B=xt)
//       finm[n][h] = sum_c x[c][n]*Wi[h][c] + bi[h]   (A=xt, B=Wib bf16x8)
//     1 xt frag + 2 wj + 2 wi frags -> 4 MFMAs per kstep.
//   2592 compute waves (10/CU) vs r5's 1296 — pure TLP doubling; total
//   staging work and xb write volume unchanged (each block owns its 16 n).
// ---------------------------------------------------------------------------
__global__ __launch_bounds__(256, 2)
void k_fused12(const float* __restrict__ feat,
               const __bf16* __restrict__ Wib, const __bf16* __restrict__ Wjb,
               const float* __restrict__ bi, const float* __restrict__ bj,
               __bf16* __restrict__ xb, __bf16* __restrict__ fj,
               __bf16* __restrict__ finm) {
    const int b = blockIdx.x;
    const int t = threadIdx.x;
    __shared__ __bf16 xt[16][520];
    const int n0 = b * 16;
    // ---- stage: c = (t>>2) + 64p, n = n0 + 4*(t&3) + j ----
    {
        const int g  = t & 3;          // n-quad
        const int c8 = t >> 2;         // 0..63
        const int nq = 4 * g;
        #pragma unroll
        for (int p = 0; p < 8; p++) {
            const int c = c8 + 64 * p;
            float4 v = *(const float4*)(feat + (size_t)c * NN + n0 + nq);
            bf16x4 o;
            o[0] = (__bf16)v.x; o[1] = (__bf16)v.y;
            o[2] = (__bf16)v.z; o[3] = (__bf16)v.w;
            *(bf16x4*)(xb + (size_t)c * NN + n0 + nq) = o;
            xt[nq + 0][c] = o[0];
            xt[nq + 1][c] = o[1];
            xt[nq + 2][c] = o[2];
            xt[nq + 3][c] = o[3];
        }
    }
    __syncthreads();
    // ---- compute (r5 verified mapping, n-tile index = 0) ----
    const int w    = t >> 6;              // 0..3 ; h0 = 32w
    const int lane = t & 63;
    const int l16  = lane & 15;
    const int q    = lane >> 4;
    const int h0   = w * 32;
    f32x4 afj[2] = {};                    // fj  : [i=h-16tile]
    f32x4 afi[2] = {};                    // finm: [tt=h-16tile]
    #pragma unroll 4
    for (int k = 0; k < 512; k += 32) {
        bf16x8 ln, wj[2], wi[2];
        ln = *(const bf16x8*)&xt[l16][k + q * 8];
        #pragma unroll
        for (int i = 0; i < 2; i++)
            wj[i] = *(const bf16x8*)&Wjb[(size_t)(h0 + 16 * i + l16) * C_ + k + q * 8];
        #pragma unroll
        for (int i = 0; i < 2; i++)
            wi[i] = *(const bf16x8*)&Wib[(size_t)(h0 + 16 * i + l16) * C_ + k + q * 8];
        #pragma unroll
        for (int i = 0; i < 2; i++) {
            afj[i] = __builtin_amdgcn_mfma_f32_16x16x32_bf16(wj[i], ln, afj[i], 0, 0, 0);
            afi[i] = __builtin_amdgcn_mfma_f32_16x16x32_bf16(ln, wi[i], afi[i], 0, 0, 0);
        }
    }
    float4 bjv[2];
    bjv[0] = *(const float4*)(bj + h0 + q * 4);
    bjv[1] = *(const float4*)(bj + h0 + 16 + q * 4);
    float biv[2];
    biv[0] = bi[h0 + l16];
    biv[1] = bi[h0 + 16 + l16];
    #pragma unroll
    for (int i = 0; i < 2; i++)
        #pragma unroll
        for (int r = 0; r < 4; r++) {
            {   // fj: h = h0+16i+q*4+r, n = n0+l16
                int h = h0 + 16 * i + q * 4 + r;
                int n = n0 + l16;
                fj[(size_t)h * NN + n] = (__bf16)(afj[i][r] + (&bjv[i].x)[r]);
            }
            {   // finm: n = n0+q*4+r, h = h0+16i+l16
                int n = n0 + q * 4 + r;
                int h = h0 + 16 * i + l16;
                finm[(size_t)n * HS + h] = (__bf16)(afi[i][r] + biv[i]);
            }
        }
}

// ---------------------------------------------------------------------------
// K2 (G3): Mtf[c][h] += sum_n xb[c][n] * fj[h][n]   (fp32 atomics)
//   r5 verbatim (frozen for attribution).
// ---------------------------------------------------------------------------
__global__ __launch_bounds__(256, 2)
void k_gemm3(const __bf16* __restrict__ xb, const __bf16* __restrict__ fj,
             float* __restrict__ Mtf) {
    __shared__ float red[4][64][17];
    const int b    = blockIdx.x;
    const int t    = threadIdx.x;
    const int v    = t >> 6;
    const int lane = t & 63;
    const int l16  = lane & 15;
    const int q    = lane >> 4;
    const int tile = b & 63, g = b >> 6;
    const int c0 = (tile >> 2) * 32, h0 = (tile & 3) * 32;
    const int chunk = g * 4 + v;               // 0..31
    const int s0 = (chunk * 324) >> 5;
    const int s1 = ((chunk + 1) * 324) >> 5;
    f32x4 acc[2][2] = {};
    bf16x8 a[2], bb[2];
    {   // preload s0
        const int k = s0 * 32;
        a[0]  = *(const bf16x8*)(xb + (size_t)(c0 + l16) * NN + k + q * 8);
        a[1]  = *(const bf16x8*)(xb + (size_t)(c0 + 16 + l16) * NN + k + q * 8);
        bb[0] = *(const bf16x8*)(fj + (size_t)(h0 + l16) * NN + k + q * 8);
        bb[1] = *(const bf16x8*)(fj + (size_t)(h0 + 16 + l16) * NN + k + q * 8);
    }
    for (int s = s0; s < s1 - 1; s++) {
        const int kn = (s + 1) * 32;
        bf16x8 a2[2], b2[2];
        a2[0] = *(const bf16x8*)(xb + (size_t)(c0 + l16) * NN + kn + q * 8);
        a2[1] = *(const bf16x8*)(xb + (size_t)(c0 + 16 + l16) * NN + kn + q * 8);
        b2[0] = *(const bf16x8*)(fj + (size_t)(h0 + l16) * NN + kn + q * 8);
        b2[1] = *(const bf16x8*)(fj + (size_t)(h0 + 16 + l16) * NN + kn + q * 8);
        #pragma unroll
        for (int i = 0; i < 2; i++)
            #pragma unroll
            for (int tt = 0; tt < 2; tt++)
                acc[i][tt] = __builtin_amdgcn_mfma_f32_16x16x32_bf16(a[i], bb[tt], acc[i][tt], 0, 0, 0);
        a[0] = a2[0]; a[1] = a2[1]; bb[0] = b2[0]; bb[1] = b2[1];
    }
    #pragma unroll
    for (int i = 0; i < 2; i++)
        #pragma unroll
        for (int tt = 0; tt < 2; tt++)
            acc[i][tt] = __builtin_amdgcn_mfma_f32_16x16x32_bf16(a[i], bb[tt], acc[i][tt], 0, 0, 0);
    #pragma unroll
    for (int i = 0; i < 2; i++)
        #pragma unroll
        for (int tt = 0; tt < 2; tt++)
            #pragma unroll
            for (int r = 0; r < 4; r++)
                red[v][lane][i * 8 + tt * 4 + r] = acc[i][tt][r];
    __syncthreads();
    #pragma unroll
    for (int u = 0; u < 4; u++) {
        const int idx = t * 4 + u;
        const int lane_e = idx >> 4, j = idx & 15;
        float s = red[0][lane_e][j] + red[1][lane_e][j]
                + red[2][lane_e][j] + red[3][lane_e][j];
        const int i = j >> 3, tt = (j >> 2) & 1, r = j & 3;
        const int qe = lane_e >> 4, le = lane_e & 15;
        const int c = c0 + 16 * i + qe * 4 + r;
        const int h = h0 + 16 * tt + le;
        atomicAdd(&Mtf[c * HS + h], s);
    }
}

// ---------------------------------------------------------------------------
// K3 (G4 + scale + residual), 648 blocks x 256 thr — r5 verbatim (frozen).
// ---------------------------------------------------------------------------
__global__ __launch_bounds__(256, 2)
void k_gemm4(const float* __restrict__ Mtf, const __bf16* __restrict__ finm,
             const float* __restrict__ feat, const float* __restrict__ agg,
             float* __restrict__ out) {
    __shared__ float lds_out[128][64];         // 32 KB
    const int t    = threadIdx.x;
    const int wv   = t >> 6;                   // wave in block
    const int w    = blockIdx.x * 4 + wv;      // 0..2591
    const int lane = t & 63;
    const int l16  = lane & 15;
    const int q    = lane >> 4;
    const int c0 = (w & 15) * 32, n0 = (w >> 4) * 64;
    const float scale = agg[0] * (1.0f / (float)NN);
    f32x4 acc[2][4] = {};
    #pragma unroll
    for (int k = 0; k < 128; k += 32) {
        bf16x8 a[2], bfr[4];
        #pragma unroll
        for (int i = 0; i < 2; i++)
            a[i] = load_f32x8_as_bf16(Mtf + (c0 + 16 * i + l16) * HS + k + q * 8);
        #pragma unroll
        for (int tt = 0; tt < 4; tt++)
            bfr[tt] = *(const bf16x8*)(finm + (size_t)(n0 + 16 * tt + l16) * HS + k + q * 8);
        #pragma unroll
        for (int i = 0; i < 2; i++)
            #pragma unroll
            for (int tt = 0; tt < 4; tt++)
                acc[i][tt] = __builtin_amdgcn_mfma_f32_16x16x32_bf16(a[i], bfr[tt], acc[i][tt], 0, 0, 0);
    }
    // scaled acc -> LDS (row = local c, col = local n)
    #pragma unroll
    for (int i = 0; i < 2; i++)
        #pragma unroll
        for (int tt = 0; tt < 4; tt++)
            #pragma unroll
            for (int r = 0; r < 4; r++)
                lds_out[wv * 32 + 16 * i + q * 4 + r][16 * tt + l16] = scale * acc[i][tt][r];
    __syncthreads();
    // streaming epilogue: thread covers rows {t>>2, t>>2+64}, cols (t&3)*4 + j4*16
    const int c0b = ((blockIdx.x * 4) & 15) * 32;
    const int n0b = ((blockIdx.x * 4) >> 4) * 64;
    #pragma unroll
    for (int rr = 0; rr < 2; rr++) {
        const int row = (t >> 2) + 64 * rr;
        const size_t gbase = (size_t)(c0b + row) * NN + n0b;
        float4 fv[4];
        #pragma unroll
        for (int j4 = 0; j4 < 4; j4++) {
            const int col = (t & 3) * 4 + j4 * 16;
            fv[j4] = *(const float4*)(feat + gbase + col);
        }
        #pragma unroll
        for (int j4 = 0; j4 < 4; j4++) {
            const int col = (t & 3) * 4 + j4 * 16;
            f32x4 v = *(const f32x4*)&lds_out[row][col];
            float4 o;
            o.x = fv[j4].x + v[0]; o.y = fv[j4].y + v[1];
            o.z = fv[j4].z + v[2]; o.w = fv[j4].w + v[3];
            *(float4*)(out + gbase + col) = o;
        }
    }
}

// ---------------------------------------------------------------------------
// Workspace layout (bytes):
//   xb   @ 0          : 10,616,832   bf16 [C][N]
//   fj   @ 10,616,832 : 2,654,208    bf16 [HS][N]
//   finm @ 13,271,040 : 2,654,208    bf16 [N][HS]
//   Mtf  @ 15,925,248 : 262,144      fp32 [C][HS]
//   Wjb  @ 16,187,392 : 131,072      bf16 [HS][C]
//   Wib  @ 16,318,464 : 131,072      bf16 [HS][C]   total ~16.4 MB
// ---------------------------------------------------------------------------
extern "C" void kernel_launch(void* const* d_in, const int* in_sizes, int n_in,
                              void* d_out, int out_size, void* d_ws, size_t ws_size,
                              hipStream_t stream) {
    const float* feat = (const float*)d_in[0];
    const float* Wi   = (const float*)d_in[1];
    const float* bi   = (const float*)d_in[2];
    const float* Wj   = (const float*)d_in[3];
    const float* bj   = (const float*)d_in[4];
    const float* agg  = (const float*)d_in[5];
    float* out = (float*)d_out;

    char* ws = (char*)d_ws;
    __bf16* xb   = (__bf16*)(ws);
    __bf16* fj   = (__bf16*)(ws + 10616832);
    __bf16* finm = (__bf16*)(ws + 13271040);
    float*  Mtf  = (float*) (ws + 15925248);
    __bf16* Wjb  = (__bf16*)(ws + 16187392);
    __bf16* Wib  = (__bf16*)(ws + 16318464);

    k_prep   <<<20,  256, 0, stream>>>(Wi, Wj, Wib, Wjb, Mtf);
    k_fused12<<<648, 256, 0, stream>>>(feat, Wib, Wjb, bi, bj, xb, fj, finm);
    k_gemm3  <<<512, 256, 0, stream>>>(xb, fj, Mtf);
    k_gemm4  <<<648, 256, 0, stream>>>(Mtf, finm, feat, agg, out);
}

// Round 7
// 129.625 us; speedup vs baseline: 1.0677x; 1.0677x over previous
//
#include <hip/hip_runtime.h>
#include <hip/hip_bf16.h>

#define C_   512
#define HS   128
#define NN   10368   // 18*24*24 ; 324 n-tiles of 32

typedef __bf16 bf16x8 __attribute__((ext_vector_type(8)));
typedef __bf16 bf16x4 __attribute__((ext_vector_type(4)));
typedef __bf16 bf16x2 __attribute__((ext_vector_type(2)));
typedef float  f32x4  __attribute__((ext_vector_type(4)));

__device__ __forceinline__ bf16x8 load_f32x8_as_bf16(const float* __restrict__ p) {
    float4 v0 = *(const float4*)p;
    float4 v1 = *(const float4*)(p + 4);
    bf16x8 o;
    o[0] = (__bf16)v0.x; o[1] = (__bf16)v0.y; o[2] = (__bf16)v0.z; o[3] = (__bf16)v0.w;
    o[4] = (__bf16)v1.x; o[5] = (__bf16)v1.y; o[6] = (__bf16)v1.z; o[7] = (__bf16)v1.w;
    return o;
}

// ---------------------------------------------------------------------------
// K0 (prep): 20 blocks x 256.  (r5 verbatim, frozen)
//   b<4 : convert Wj,Wi fp32->bf16.   b>=4: zero Mtf fp32 [C][HS].
// ---------------------------------------------------------------------------
__global__ __launch_bounds__(256, 2)
void k_prep(const float* __restrict__ Wi, const float* __restrict__ Wj,
            __bf16* __restrict__ Wib, __bf16* __restrict__ Wjb,
            float* __restrict__ Mtf) {
    const int b = blockIdx.x;
    const int t = threadIdx.x;
    if (b < 4) {   // b=0,1 -> Wjb ; b=2,3 -> Wib
        const float* src = (b < 2) ? Wj : Wi;
        __bf16* dst = (b < 2) ? Wjb : Wib;
        const int off = (b & 1) * 32768;
        #pragma unroll 4
        for (int u = 0; u < 32; u++) {
            const int idx = off + u * 1024 + t * 4;
            float4 v = *(const float4*)(src + idx);
            bf16x4 o;
            o[0] = (__bf16)v.x; o[1] = (__bf16)v.y;
            o[2] = (__bf16)v.z; o[3] = (__bf16)v.w;
            *(bf16x4*)(dst + idx) = o;
        }
    } else {       // zero Mtf: 16 blocks x 256 thr x 16 floats
        const int z = b - 4;
        f32x4 zv = {0.f, 0.f, 0.f, 0.f};
        float* p = Mtf + z * 4096 + t * 16;
        *(f32x4*)(p) = zv; *(f32x4*)(p + 4) = zv;
        *(f32x4*)(p + 8) = zv; *(f32x4*)(p + 12) = zv;
    }
}

// ---------------------------------------------------------------------------
// K1 (fused transpose + G1 + G2), 324 blocks x 512 thr (8 waves):
//   Same 324-block geometry as r5 (weight L2 traffic UNCHANGED ~83 MB),
//   but h-dim split across 8 waves (16 h-rows each) instead of 4 (32 each):
//   2x waves/CU at identical traffic. r6 showed splitting the n-tile
//   doubles weight traffic and regresses; splitting h does not.
//   stage (float4, r5-verified pattern): thread = (n-quad t&7, c-lane t>>3),
//     8 float4 feat loads, bf16x4 xb stores, scalar scatter into xt[32][520].
//   compute (wave w: h0 = 16w) — round-2 harness-verified 8-wave mapping:
//     fj[h][n]   = sum_c Wj[h][c]*x[c][n] + bj[h]   (A=Wjb bf16x8, B=xt)
//     finm[n][h] = sum_c x[c][n]*Wi[h][c] + bi[h]   (A=xt, B=Wib bf16x8)
//     per kstep: 2 ln + 1 wj + 1 wi frags -> 4 MFMAs.
// ---------------------------------------------------------------------------
__global__ __launch_bounds__(512, 2)
void k_fused12(const float* __restrict__ feat,
               const __bf16* __restrict__ Wib, const __bf16* __restrict__ Wjb,
               const float* __restrict__ bi, const float* __restrict__ bj,
               __bf16* __restrict__ xb, __bf16* __restrict__ fj,
               __bf16* __restrict__ finm) {
    const int b = blockIdx.x;
    const int t = threadIdx.x;
    __shared__ __bf16 xt[32][520];
    const int n0 = b * 32;
    // ---- stage: c = (t>>3) + 64p, n = n0 + 4*(t&7) + j ----
    {
        const int g  = t & 7;          // n-quad
        const int c8 = t >> 3;         // 0..63
        const int nq = 4 * g;
        #pragma unroll
        for (int p = 0; p < 8; p++) {
            const int c = c8 + 64 * p;
            float4 v = *(const float4*)(feat + (size_t)c * NN + n0 + nq);
            bf16x4 o;
            o[0] = (__bf16)v.x; o[1] = (__bf16)v.y;
            o[2] = (__bf16)v.z; o[3] = (__bf16)v.w;
            *(bf16x4*)(xb + (size_t)c * NN + n0 + nq) = o;
            xt[nq + 0][c] = o[0];
            xt[nq + 1][c] = o[1];
            xt[nq + 2][c] = o[2];
            xt[nq + 3][c] = o[3];
        }
    }
    __syncthreads();
    // ---- compute (round-2 harness-verified 8-wave mapping) ----
    const int w    = t >> 6;              // 0..7 ; h0 = 16w
    const int lane = t & 63;
    const int l16  = lane & 15;
    const int q    = lane >> 4;
    const int h0   = w * 16;
    f32x4 afj[2] = {};                    // fj  : D[row=h][col=n], n-tiles tt
    f32x4 afi[2] = {};                    // finm: D[row=n][col=h], n-tiles i2
    #pragma unroll 4
    for (int k = 0; k < 512; k += 32) {
        bf16x8 ln0 = *(const bf16x8*)&xt[l16][k + q * 8];
        bf16x8 ln1 = *(const bf16x8*)&xt[16 + l16][k + q * 8];
        bf16x8 wjf = *(const bf16x8*)&Wjb[(size_t)(h0 + l16) * C_ + k + q * 8];
        bf16x8 wif = *(const bf16x8*)&Wib[(size_t)(h0 + l16) * C_ + k + q * 8];
        afj[0] = __builtin_amdgcn_mfma_f32_16x16x32_bf16(wjf, ln0, afj[0], 0, 0, 0);
        afj[1] = __builtin_amdgcn_mfma_f32_16x16x32_bf16(wjf, ln1, afj[1], 0, 0, 0);
        afi[0] = __builtin_amdgcn_mfma_f32_16x16x32_bf16(ln0, wif, afi[0], 0, 0, 0);
        afi[1] = __builtin_amdgcn_mfma_f32_16x16x32_bf16(ln1, wif, afi[1], 0, 0, 0);
    }
    const float4 bjv = *(const float4*)(bj + h0 + q * 4);   // 16B-aligned
    const float  biv = bi[h0 + l16];
    #pragma unroll
    for (int tt = 0; tt < 2; tt++)
        #pragma unroll
        for (int r = 0; r < 4; r++) {
            const int h = h0 + q * 4 + r;
            const int n = n0 + 16 * tt + l16;
            fj[(size_t)h * NN + n] = (__bf16)(afj[tt][r] + (&bjv.x)[r]);
        }
    #pragma unroll
    for (int i2 = 0; i2 < 2; i2++)
        #pragma unroll
        for (int r = 0; r < 4; r++) {
            const int n = n0 + 16 * i2 + q * 4 + r;
            const int h = h0 + l16;
            finm[(size_t)n * HS + h] = (__bf16)(afi[i2][r] + biv);
        }
}

// ---------------------------------------------------------------------------
// K2 (G3): Mtf[c][h] += sum_n xb[c][n] * fj[h][n]   (fp32 atomics)
//   r5 verbatim (frozen for attribution).
// ---------------------------------------------------------------------------
__global__ __launch_bounds__(256, 2)
void k_gemm3(const __bf16* __restrict__ xb, const __bf16* __restrict__ fj,
             float* __restrict__ Mtf) {
    __shared__ float red[4][64][17];
    const int b    = blockIdx.x;
    const int t    = threadIdx.x;
    const int v    = t >> 6;
    const int lane = t & 63;
    const int l16  = lane & 15;
    const int q    = lane >> 4;
    const int tile = b & 63, g = b >> 6;
    const int c0 = (tile >> 2) * 32, h0 = (tile & 3) * 32;
    const int chunk = g * 4 + v;               // 0..31
    const int s0 = (chunk * 324) >> 5;
    const int s1 = ((chunk + 1) * 324) >> 5;
    f32x4 acc[2][2] = {};
    bf16x8 a[2], bb[2];
    {   // preload s0
        const int k = s0 * 32;
        a[0]  = *(const bf16x8*)(xb + (size_t)(c0 + l16) * NN + k + q * 8);
        a[1]  = *(const bf16x8*)(xb + (size_t)(c0 + 16 + l16) * NN + k + q * 8);
        bb[0] = *(const bf16x8*)(fj + (size_t)(h0 + l16) * NN + k + q * 8);
        bb[1] = *(const bf16x8*)(fj + (size_t)(h0 + 16 + l16) * NN + k + q * 8);
    }
    for (int s = s0; s < s1 - 1; s++) {
        const int kn = (s + 1) * 32;
        bf16x8 a2[2], b2[2];
        a2[0] = *(const bf16x8*)(xb + (size_t)(c0 + l16) * NN + kn + q * 8);
        a2[1] = *(const bf16x8*)(xb + (size_t)(c0 + 16 + l16) * NN + kn + q * 8);
        b2[0] = *(const bf16x8*)(fj + (size_t)(h0 + l16) * NN + kn + q * 8);
        b2[1] = *(const bf16x8*)(fj + (size_t)(h0 + 16 + l16) * NN + kn + q * 8);
        #pragma unroll
        for (int i = 0; i < 2; i++)
            #pragma unroll
            for (int tt = 0; tt < 2; tt++)
                acc[i][tt] = __builtin_amdgcn_mfma_f32_16x16x32_bf16(a[i], bb[tt], acc[i][tt], 0, 0, 0);
        a[0] = a2[0]; a[1] = a2[1]; bb[0] = b2[0]; bb[1] = b2[1];
    }
    #pragma unroll
    for (int i = 0; i < 2; i++)
        #pragma unroll
        for (int tt = 0; tt < 2; tt++)
            acc[i][tt] = __builtin_amdgcn_mfma_f32_16x16x32_bf16(a[i], bb[tt], acc[i][tt], 0, 0, 0);
    #pragma unroll
    for (int i = 0; i < 2; i++)
        #pragma unroll
        for (int tt = 0; tt < 2; tt++)
            #pragma unroll
            for (int r = 0; r < 4; r++)
                red[v][lane][i * 8 + tt * 4 + r] = acc[i][tt][r];
    __syncthreads();
    #pragma unroll
    for (int u = 0; u < 4; u++) {
        const int idx = t * 4 + u;
        const int lane_e = idx >> 4, j = idx & 15;
        float s = red[0][lane_e][j] + red[1][lane_e][j]
                + red[2][lane_e][j] + red[3][lane_e][j];
        const int i = j >> 3, tt = (j >> 2) & 1, r = j & 3;
        const int qe = lane_e >> 4, le = lane_e & 15;
        const int c = c0 + 16 * i + qe * 4 + r;
        const int h = h0 + 16 * tt + le;
        atomicAdd(&Mtf[c * HS + h], s);
    }
}

// ---------------------------------------------------------------------------
// K3 (G4 + scale + residual), 648 blocks x 256 thr — r5 verbatim (frozen).
// ---------------------------------------------------------------------------
__global__ __launch_bounds__(256, 2)
void k_gemm4(const float* __restrict__ Mtf, const __bf16* __restrict__ finm,
             const float* __restrict__ feat, const float* __restrict__ agg,
             float* __restrict__ out) {
    __shared__ float lds_out[128][64];         // 32 KB
    const int t    = threadIdx.x;
    const int wv   = t >> 6;                   // wave in block
    const int w    = blockIdx.x * 4 + wv;      // 0..2591
    const int lane = t & 63;
    const int l16  = lane & 15;
    const int q    = lane >> 4;
    const int c0 = (w & 15) * 32, n0 = (w >> 4) * 64;
    const float scale = agg[0] * (1.0f / (float)NN);
    f32x4 acc[2][4] = {};
    #pragma unroll
    for (int k = 0; k < 128; k += 32) {
        bf16x8 a[2], bfr[4];
        #pragma unroll
        for (int i = 0; i < 2; i++)
            a[i] = load_f32x8_as_bf16(Mtf + (c0 + 16 * i + l16) * HS + k + q * 8);
        #pragma unroll
        for (int tt = 0; tt < 4; tt++)
            bfr[tt] = *(const bf16x8*)(finm + (size_t)(n0 + 16 * tt + l16) * HS + k + q * 8);
        #pragma unroll
        for (int i = 0; i < 2; i++)
            #pragma unroll
            for (int tt = 0; tt < 4; tt++)
                acc[i][tt] = __builtin_amdgcn_mfma_f32_16x16x32_bf16(a[i], bfr[tt], acc[i][tt], 0, 0, 0);
    }
    // scaled acc -> LDS (row = local c, col = local n)
    #pragma unroll
    for (int i = 0; i < 2; i++)
        #pragma unroll
        for (int tt = 0; tt < 4; tt++)
            #pragma unroll
            for (int r = 0; r < 4; r++)
                lds_out[wv * 32 + 16 * i + q * 4 + r][16 * tt + l16] = scale * acc[i][tt][r];
    __syncthreads();
    // streaming epilogue: thread covers rows {t>>2, t>>2+64}, cols (t&3)*4 + j4*16
    const int c0b = ((blockIdx.x * 4) & 15) * 32;
    const int n0b = ((blockIdx.x * 4) >> 4) * 64;
    #pragma unroll
    for (int rr = 0; rr < 2; rr++) {
        const int row = (t >> 2) + 64 * rr;
        const size_t gbase = (size_t)(c0b + row) * NN + n0b;
        float4 fv[4];
        #pragma unroll
        for (int j4 = 0; j4 < 4; j4++) {
            const int col = (t & 3) * 4 + j4 * 16;
            fv[j4] = *(const float4*)(feat + gbase + col);
        }
        #pragma unroll
        for (int j4 = 0; j4 < 4; j4++) {
            const int col = (t & 3) * 4 + j4 * 16;
            f32x4 v = *(const f32x4*)&lds_out[row][col];
            float4 o;
            o.x = fv[j4].x + v[0]; o.y = fv[j4].y + v[1];
            o.z = fv[j4].z + v[2]; o.w = fv[j4].w + v[3];
            *(float4*)(out + gbase + col) = o;
        }
    }
}

// ---------------------------------------------------------------------------
// Workspace layout (bytes):
//   xb   @ 0          : 10,616,832   bf16 [C][N]
//   fj   @ 10,616,832 : 2,654,208    bf16 [HS][N]
//   finm @ 13,271,040 : 2,654,208    bf16 [N][HS]
//   Mtf  @ 15,925,248 : 262,144      fp32 [C][HS]
//   Wjb  @ 16,187,392 : 131,072      bf16 [HS][C]
//   Wib  @ 16,318,464 : 131,072      bf16 [HS][C]   total ~16.4 MB
// ---------------------------------------------------------------------------
extern "C" void kernel_launch(void* const* d_in, const int* in_sizes, int n_in,
                              void* d_out, int out_size, void* d_ws, size_t ws_size,
                              hipStream_t stream) {
    const float* feat = (const float*)d_in[0];
    const float* Wi   = (const float*)d_in[1];
    const float* bi   = (const float*)d_in[2];
    const float* Wj   = (const float*)d_in[3];
    const float* bj   = (const float*)d_in[4];
    const float* agg  = (const float*)d_in[5];
    float* out = (float*)d_out;

    char* ws = (char*)d_ws;
    __bf16* xb   = (__bf16*)(ws);
    __bf16* fj   = (__bf16*)(ws + 10616832);
    __bf16* finm = (__bf16*)(ws + 13271040);
    float*  Mtf  = (float*) (ws + 15925248);
    __bf16* Wjb  = (__bf16*)(ws + 16187392);
    __bf16* Wib  = (__bf16*)(ws + 16318464);

    k_prep   <<<20,  256, 0, stream>>>(Wi, Wj, Wib, Wjb, Mtf);
    k_fused12<<<324, 512, 0, stream>>>(feat, Wib, Wjb, bi, bj, xb, fj, finm);
    k_gemm3  <<<512, 256, 0, stream>>>(xb, fj, Mtf);
    k_gemm4  <<<648, 256, 0, stream>>>(Mtf, finm, feat, agg, out);
}

// Round 8
// 126.946 us; speedup vs baseline: 1.0902x; 1.0211x over previous
//
#include <hip/hip_runtime.h>
#include <hip/hip_bf16.h>

#define C_   512
#define HS   128
#define NN   10368   // 18*24*24 ; 324 n-tiles of 32

typedef __bf16 bf16x8 __attribute__((ext_vector_type(8)));
typedef __bf16 bf16x4 __attribute__((ext_vector_type(4)));
typedef __bf16 bf16x2 __attribute__((ext_vector_type(2)));
typedef float  f32x4  __attribute__((ext_vector_type(4)));

__device__ __forceinline__ bf16x8 load_f32x8_as_bf16(const float* __restrict__ p) {
    float4 v0 = *(const float4*)p;
    float4 v1 = *(const float4*)(p + 4);
    bf16x8 o;
    o[0] = (__bf16)v0.x; o[1] = (__bf16)v0.y; o[2] = (__bf16)v0.z; o[3] = (__bf16)v0.w;
    o[4] = (__bf16)v1.x; o[5] = (__bf16)v1.y; o[6] = (__bf16)v1.z; o[7] = (__bf16)v1.w;
    return o;
}

// ---------------------------------------------------------------------------
// K0 (prep): 80 blocks x 256 thr.
//   b<64 : gid = b*256+t in [0,16384): convert float4 #gid of BOTH Wj and Wi
//          (fp32->bf16).  2 loads + 2 stores per thread, fully parallel.
//   b>=64: zero Mtf fp32 [C][HS] (16 blocks, r5-verified code).
// ---------------------------------------------------------------------------
__global__ __launch_bounds__(256, 2)
void k_prep(const float* __restrict__ Wi, const float* __restrict__ Wj,
            __bf16* __restrict__ Wib, __bf16* __restrict__ Wjb,
            float* __restrict__ Mtf) {
    const int b = blockIdx.x;
    const int t = threadIdx.x;
    if (b < 64) {
        const int idx = (b * 256 + t) * 4;          // 0..65532
        float4 vj = *(const float4*)(Wj + idx);
        float4 vi = *(const float4*)(Wi + idx);
        bf16x4 oj, oi;
        oj[0] = (__bf16)vj.x; oj[1] = (__bf16)vj.y; oj[2] = (__bf16)vj.z; oj[3] = (__bf16)vj.w;
        oi[0] = (__bf16)vi.x; oi[1] = (__bf16)vi.y; oi[2] = (__bf16)vi.z; oi[3] = (__bf16)vi.w;
        *(bf16x4*)(Wjb + idx) = oj;
        *(bf16x4*)(Wib + idx) = oi;
    } else {       // zero Mtf: 16 blocks x 256 thr x 16 floats
        const int z = b - 64;
        f32x4 zv = {0.f, 0.f, 0.f, 0.f};
        float* p = Mtf + z * 4096 + t * 16;
        *(f32x4*)(p) = zv; *(f32x4*)(p + 4) = zv;
        *(f32x4*)(p + 8) = zv; *(f32x4*)(p + 12) = zv;
    }
}

// ---------------------------------------------------------------------------
// K1 (fused transpose + G1 + G2), 324 blocks x 512 thr (8 waves):
//   stage REWRITTEN: thread = (n-quad t&7, c-pair t>>3); per iter loads
//     float4 from rows c and c+1 (16B/lane, coalesced), stores bf16x4 to xb
//     (both rows), and 4x bf16x2 (4B) into xt — the r0/r1-verified paired-c
//     LDS write pattern. 16 ds_write_b32/thread vs r7's 32 ds_write_u16.
//   compute: r7 verbatim (round-2 harness-verified 8-wave mapping):
//     fj[h][n]   = sum_c Wj[h][c]*x[c][n] + bj[h]   (A=Wjb bf16x8, B=xt)
//     finm[n][h] = sum_c x[c][n]*Wi[h][c] + bi[h]   (A=xt, B=Wib bf16x8)
// ---------------------------------------------------------------------------
__global__ __launch_bounds__(512, 2)
void k_fused12(const float* __restrict__ feat,
               const __bf16* __restrict__ Wib, const __bf16* __restrict__ Wjb,
               const float* __restrict__ bi, const float* __restrict__ bj,
               __bf16* __restrict__ xb, __bf16* __restrict__ fj,
               __bf16* __restrict__ finm) {
    const int b = blockIdx.x;
    const int t = threadIdx.x;
    __shared__ __bf16 xt[32][520];
    const int n0 = b * 32;
    // ---- stage: c = 2*(cp + 64p) (+1), n = n0 + 4*(t&7) + j ----
    {
        const int g  = t & 7;          // n-quad
        const int cp = t >> 3;         // 0..63
        const int nq = 4 * g;
        #pragma unroll
        for (int p = 0; p < 4; p++) {
            const int c = 2 * (cp + 64 * p);       // even, 0..510
            const float* s = feat + (size_t)c * NN + n0 + nq;
            float4 v0 = *(const float4*)s;
            float4 v1 = *(const float4*)(s + NN);
            bf16x4 o0, o1;
            o0[0] = (__bf16)v0.x; o0[1] = (__bf16)v0.y; o0[2] = (__bf16)v0.z; o0[3] = (__bf16)v0.w;
            o1[0] = (__bf16)v1.x; o1[1] = (__bf16)v1.y; o1[2] = (__bf16)v1.z; o1[3] = (__bf16)v1.w;
            *(bf16x4*)(xb + (size_t)c * NN + n0 + nq)       = o0;
            *(bf16x4*)(xb + (size_t)(c + 1) * NN + n0 + nq) = o1;
            #pragma unroll
            for (int j = 0; j < 4; j++) {
                bf16x2 pk; pk[0] = o0[j]; pk[1] = o1[j];
                *(bf16x2*)&xt[nq + j][c] = pk;     // 4B-aligned (c even)
            }
        }
    }
    __syncthreads();
    // ---- compute (r7 verbatim, round-2 harness-verified 8-wave mapping) ----
    const int w    = t >> 6;              // 0..7 ; h0 = 16w
    const int lane = t & 63;
    const int l16  = lane & 15;
    const int q    = lane >> 4;
    const int h0   = w * 16;
    f32x4 afj[2] = {};                    // fj  : D[row=h][col=n], n-tiles tt
    f32x4 afi[2] = {};                    // finm: D[row=n][col=h], n-tiles i2
    #pragma unroll 4
    for (int k = 0; k < 512; k += 32) {
        bf16x8 ln0 = *(const bf16x8*)&xt[l16][k + q * 8];
        bf16x8 ln1 = *(const bf16x8*)&xt[16 + l16][k + q * 8];
        bf16x8 wjf = *(const bf16x8*)&Wjb[(size_t)(h0 + l16) * C_ + k + q * 8];
        bf16x8 wif = *(const bf16x8*)&Wib[(size_t)(h0 + l16) * C_ + k + q * 8];
        afj[0] = __builtin_amdgcn_mfma_f32_16x16x32_bf16(wjf, ln0, afj[0], 0, 0, 0);
        afj[1] = __builtin_amdgcn_mfma_f32_16x16x32_bf16(wjf, ln1, afj[1], 0, 0, 0);
        afi[0] = __builtin_amdgcn_mfma_f32_16x16x32_bf16(ln0, wif, afi[0], 0, 0, 0);
        afi[1] = __builtin_amdgcn_mfma_f32_16x16x32_bf16(ln1, wif, afi[1], 0, 0, 0);
    }
    const float4 bjv = *(const float4*)(bj + h0 + q * 4);   // 16B-aligned
    const float  biv = bi[h0 + l16];
    #pragma unroll
    for (int tt = 0; tt < 2; tt++)
        #pragma unroll
        for (int r = 0; r < 4; r++) {
            const int h = h0 + q * 4 + r;
            const int n = n0 + 16 * tt + l16;
            fj[(size_t)h * NN + n] = (__bf16)(afj[tt][r] + (&bjv.x)[r]);
        }
    #pragma unroll
    for (int i2 = 0; i2 < 2; i2++)
        #pragma unroll
        for (int r = 0; r < 4; r++) {
            const int n = n0 + 16 * i2 + q * 4 + r;
            const int h = h0 + l16;
            finm[(size_t)n * HS + h] = (__bf16)(afi[i2][r] + biv);
        }
}

// ---------------------------------------------------------------------------
// K2 (G3): Mtf[c][h] += sum_n xb[c][n] * fj[h][n]   (fp32 atomics)
//   512 blocks x 512 thr (8 waves) — round-2 harness-verified geometry
//   (chunk = g*8+v, 5-6 ksteps/wave, red[8][64][17], t*2 epilogue) with the
//   r4-verified register double-buffer.
// ---------------------------------------------------------------------------
__global__ __launch_bounds__(512, 2)
void k_gemm3(const __bf16* __restrict__ xb, const __bf16* __restrict__ fj,
             float* __restrict__ Mtf) {
    __shared__ float red[8][64][17];
    const int b    = blockIdx.x;
    const int t    = threadIdx.x;
    const int v    = t >> 6;
    const int lane = t & 63;
    const int l16  = lane & 15;
    const int q    = lane >> 4;
    const int tile = b & 63, g = b >> 6;
    const int c0 = (tile >> 2) * 32, h0 = (tile & 3) * 32;
    const int chunk = g * 8 + v;               // 0..63
    const int s0 = (chunk * 324) >> 6;
    const int s1 = ((chunk + 1) * 324) >> 6;
    f32x4 acc[2][2] = {};
    bf16x8 a[2], bb[2];
    {   // preload s0
        const int k = s0 * 32;
        a[0]  = *(const bf16x8*)(xb + (size_t)(c0 + l16) * NN + k + q * 8);
        a[1]  = *(const bf16x8*)(xb + (size_t)(c0 + 16 + l16) * NN + k + q * 8);
        bb[0] = *(const bf16x8*)(fj + (size_t)(h0 + l16) * NN + k + q * 8);
        bb[1] = *(const bf16x8*)(fj + (size_t)(h0 + 16 + l16) * NN + k + q * 8);
    }
    for (int s = s0; s < s1 - 1; s++) {
        const int kn = (s + 1) * 32;
        bf16x8 a2[2], b2[2];
        a2[0] = *(const bf16x8*)(xb + (size_t)(c0 + l16) * NN + kn + q * 8);
        a2[1] = *(const bf16x8*)(xb + (size_t)(c0 + 16 + l16) * NN + kn + q * 8);
        b2[0] = *(const bf16x8*)(fj + (size_t)(h0 + l16) * NN + kn + q * 8);
        b2[1] = *(const bf16x8*)(fj + (size_t)(h0 + 16 + l16) * NN + kn + q * 8);
        #pragma unroll
        for (int i = 0; i < 2; i++)
            #pragma unroll
            for (int tt = 0; tt < 2; tt++)
                acc[i][tt] = __builtin_amdgcn_mfma_f32_16x16x32_bf16(a[i], bb[tt], acc[i][tt], 0, 0, 0);
        a[0] = a2[0]; a[1] = a2[1]; bb[0] = b2[0]; bb[1] = b2[1];
    }
    #pragma unroll
    for (int i = 0; i < 2; i++)
        #pragma unroll
        for (int tt = 0; tt < 2; tt++)
            acc[i][tt] = __builtin_amdgcn_mfma_f32_16x16x32_bf16(a[i], bb[tt], acc[i][tt], 0, 0, 0);
    #pragma unroll
    for (int i = 0; i < 2; i++)
        #pragma unroll
        for (int tt = 0; tt < 2; tt++)
            #pragma unroll
            for (int r = 0; r < 4; r++)
                red[v][lane][i * 8 + tt * 4 + r] = acc[i][tt][r];
    __syncthreads();
    #pragma unroll
    for (int u = 0; u < 2; u++) {
        const int idx = t * 2 + u;
        const int lane_e = idx >> 4, j = idx & 15;
        float s = 0.f;
        #pragma unroll
        for (int vv = 0; vv < 8; vv++) s += red[vv][lane_e][j];
        const int i = j >> 3, tt = (j >> 2) & 1, r = j & 3;
        const int qe = lane_e >> 4, le = lane_e & 15;
        const int c = c0 + 16 * i + qe * 4 + r;
        const int h = h0 + 16 * tt + le;
        atomicAdd(&Mtf[c * HS + h], s);
    }
}

// ---------------------------------------------------------------------------
// K3 (G4 + scale + residual), 648 blocks x 256 thr — r5 verbatim (frozen).
// ---------------------------------------------------------------------------
__global__ __launch_bounds__(256, 2)
void k_gemm4(const float* __restrict__ Mtf, const __bf16* __restrict__ finm,
             const float* __restrict__ feat, const float* __restrict__ agg,
             float* __restrict__ out) {
    __shared__ float lds_out[128][64];         // 32 KB
    const int t    = threadIdx.x;
    const int wv   = t >> 6;                   // wave in block
    const int w    = blockIdx.x * 4 + wv;      // 0..2591
    const int lane = t & 63;
    const int l16  = lane & 15;
    const int q    = lane >> 4;
    const int c0 = (w & 15) * 32, n0 = (w >> 4) * 64;
    const float scale = agg[0] * (1.0f / (float)NN);
    f32x4 acc[2][4] = {};
    #pragma unroll
    for (int k = 0; k < 128; k += 32) {
        bf16x8 a[2], bfr[4];
        #pragma unroll
        for (int i = 0; i < 2; i++)
            a[i] = load_f32x8_as_bf16(Mtf + (c0 + 16 * i + l16) * HS + k + q * 8);
        #pragma unroll
        for (int tt = 0; tt < 4; tt++)
            bfr[tt] = *(const bf16x8*)(finm + (size_t)(n0 + 16 * tt + l16) * HS + k + q * 8);
        #pragma unroll
        for (int i = 0; i < 2; i++)
            #pragma unroll
            for (int tt = 0; tt < 4; tt++)
                acc[i][tt] = __builtin_amdgcn_mfma_f32_16x16x32_bf16(a[i], bfr[tt], acc[i][tt], 0, 0, 0);
    }
    // scaled acc -> LDS (row = local c, col = local n)
    #pragma unroll
    for (int i = 0; i < 2; i++)
        #pragma unroll
        for (int tt = 0; tt < 4; tt++)
            #pragma unroll
            for (int r = 0; r < 4; r++)
                lds_out[wv * 32 + 16 * i + q * 4 + r][16 * tt + l16] = scale * acc[i][tt][r];
    __syncthreads();
    // streaming epilogue: thread covers rows {t>>2, t>>2+64}, cols (t&3)*4 + j4*16
    const int c0b = ((blockIdx.x * 4) & 15) * 32;
    const int n0b = ((blockIdx.x * 4) >> 4) * 64;
    #pragma unroll
    for (int rr = 0; rr < 2; rr++) {
        const int row = (t >> 2) + 64 * rr;
        const size_t gbase = (size_t)(c0b + row) * NN + n0b;
        float4 fv[4];
        #pragma unroll
        for (int j4 = 0; j4 < 4; j4++) {
            const int col = (t & 3) * 4 + j4 * 16;
            fv[j4] = *(const float4*)(feat + gbase + col);
        }
        #pragma unroll
        for (int j4 = 0; j4 < 4; j4++) {
            const int col = (t & 3) * 4 + j4 * 16;
            f32x4 v = *(const f32x4*)&lds_out[row][col];
            float4 o;
            o.x = fv[j4].x + v[0]; o.y = fv[j4].y + v[1];
            o.z = fv[j4].z + v[2]; o.w = fv[j4].w + v[3];
            *(float4*)(out + gbase + col) = o;
        }
    }
}

// ---------------------------------------------------------------------------
// Workspace layout (bytes):
//   xb   @ 0          : 10,616,832   bf16 [C][N]
//   fj   @ 10,616,832 : 2,654,208    bf16 [HS][N]
//   finm @ 13,271,040 : 2,654,208    bf16 [N][HS]
//   Mtf  @ 15,925,248 : 262,144      fp32 [C][HS]
//   Wjb  @ 16,187,392 : 131,072      bf16 [HS][C]
//   Wib  @ 16,318,464 : 131,072      bf16 [HS][C]   total ~16.4 MB
// ---------------------------------------------------------------------------
extern "C" void kernel_launch(void* const* d_in, const int* in_sizes, int n_in,
                              void* d_out, int out_size, void* d_ws, size_t ws_size,
                              hipStream_t stream) {
    const float* feat = (const float*)d_in[0];
    const float* Wi   = (const float*)d_in[1];
    const float* bi   = (const float*)d_in[2];
    const float* Wj   = (const float*)d_in[3];
    const float* bj   = (const float*)d_in[4];
    const float* agg  = (const float*)d_in[5];
    float* out = (float*)d_out;

    char* ws = (char*)d_ws;
    __bf16* xb   = (__bf16*)(ws);
    __bf16* fj   = (__bf16*)(ws + 10616832);
    __bf16* finm = (__bf16*)(ws + 13271040);
    float*  Mtf  = (float*) (ws + 15925248);
    __bf16* Wjb  = (__bf16*)(ws + 16187392);
    __bf16* Wib  = (__bf16*)(ws + 16318464);

    k_prep   <<<80,  256, 0, stream>>>(Wi, Wj, Wib, Wjb, Mtf);
    k_fused12<<<324, 512, 0, stream>>>(feat, Wib, Wjb, bi, bj, xb, fj, finm);
    k_gemm3  <<<512, 512, 0, stream>>>(xb, fj, Mtf);
    k_gemm4  <<<648, 256, 0, stream>>>(Mtf, finm, feat, agg, out);
}